// Round 5
// baseline (311.460 us; speedup 1.0000x reference)
//
#include <hip/hip_runtime.h>

#define BLOCK 256
#define NBLOCKS 2048   // 8 blocks/CU requested; persistent grid-stride over tiles

// clang-native vector type: accepted by __builtin_nontemporal_{load,store}
typedef float vf4 __attribute__((ext_vector_type(4)));

// Prepass: pack (pos.xyz, bitcast(batch)) into a 16B-aligned float4 table.
// One aligned dwordx4 gather per endpoint in the main kernel.
extern "C" __global__ void __launch_bounds__(BLOCK) pack_pos_batch(
    const float* __restrict__ pos,      // [N,3]
    const int*  __restrict__ batch,     // [N]
    vf4* __restrict__ pos4,             // [N] out
    int N)
{
    const int i = blockIdx.x * BLOCK + threadIdx.x;
    if (i < N) {
        vf4 v;
        v.x = pos[3 * i + 0];
        v.y = pos[3 * i + 1];
        v.z = pos[3 * i + 2];
        v.w = __int_as_float(batch[i]);
        pos4[i] = v;
    }
}

template <bool PACKED>
__global__ void __launch_bounds__(BLOCK) edge_encoding_kernel(
    const float* __restrict__ pos,      // [N,3] (fallback)
    const vf4*   __restrict__ pos4,     // [N] packed
    const float* __restrict__ cells,    // [G,3,3] = 144 f32
    const int*   __restrict__ eidx,     // [2,E]
    const int*   __restrict__ pidx,     // [E]
    const int*   __restrict__ batch,    // [N] (fallback)
    float* __restrict__ out,            // [E,19]
    int E)
{
    __shared__ float s_cells[144];
    __shared__ __align__(16) float s_out[BLOCK * 19];   // 19456 B

    const int tid = threadIdx.x;
    if (tid < 144) s_cells[tid] = cells[tid];

    const int ntiles = (E + BLOCK - 1) / BLOCK;
    const int nb = gridDim.x;

    const float s3  = 1.7320508075688772f;
    const float s5  = 2.2360679774997896f;
    const float s15 = 3.872983346207417f;

    // ---- pipeline state ----
    // tile t   : gathers resident (g_ps, g_pd) + p0
    // tile t+nb: indices resident (src1, dst1, p1)
    int src1, dst1, p0, p1;
    vf4 g_ps, g_pd;

    // index load for tile tt (clamped; OOB tile -> identity values)
    auto load_idx = [&](int tt, int& s, int& d, int& p) {
        if (tt < ntiles) {
            int e = tt * BLOCK + tid;
            e = min(e, E - 1);                     // tail lanes: clamp (rows not stored)
            s = __builtin_nontemporal_load(eidx + e);
            d = __builtin_nontemporal_load(eidx + E + e);
            p = __builtin_nontemporal_load(pidx + e);
        } else { s = 0; d = 0; p = 13; }           // p=13 -> zero shift
    };
    auto gather = [&](int s, int d, vf4& a, vf4& b) {
        if (PACKED) {
            a = pos4[s];
            b = pos4[d];
        } else {
            a.x = pos[3*s+0]; a.y = pos[3*s+1]; a.z = pos[3*s+2];
            a.w = __int_as_float(batch[s]);
            b.x = pos[3*d+0]; b.y = pos[3*d+1]; b.z = pos[3*d+2];
            b.w = 0.0f;
        }
    };

    // ---- prologue: fill the pipe ----
    int t = blockIdx.x;
    {
        int s0, d0;
        load_idx(t, s0, d0, p0);
        gather(s0, d0, g_ps, g_pd);
        load_idx(t + nb, src1, dst1, p1);
    }
    __syncthreads();                               // s_cells visible; s_out free

    int tprev = -1;
    for (; t < ntiles; t += nb) {
        // 1) issue tile t+2nb index loads + tile t+nb gathers (used NEXT iter)
        int src2, dst2, p2;
        load_idx(t + 2 * nb, src2, dst2, p2);
        vf4 n_ps, n_pd;
        gather(src1, dst1, n_ps, n_pd);

        // 2) copy out tile t-nb from s_out (independent of the loads above)
        if (tprev >= 0) {
            const int nvalid  = min(BLOCK, E - tprev * BLOCK);
            const int nfloats = nvalid * 19;
            float* gout = out + (size_t)tprev * BLOCK * 19;
            const int n4 = nfloats >> 2;
            const vf4* s4 = reinterpret_cast<const vf4*>(s_out);
            vf4* g4 = reinterpret_cast<vf4*>(gout);
            for (int i = tid; i < n4; i += BLOCK)
                __builtin_nontemporal_store(s4[i], g4 + i);
            for (int i = (n4 << 2) + tid; i < nfloats; i += BLOCK)
                __builtin_nontemporal_store(s_out[i], gout + i);
        }

        // 3) compute tile t's row from gathers issued a full iteration ago
        float row[19];
        {
            const float sx = g_ps.x, sy = g_ps.y, sz = g_ps.z;
            const float dx = g_pd.x, dy = g_pd.y, dz = g_pd.z;
            const int   g  = PACKED ? __float_as_int(g_ps.w)
                                    : __float_as_int(g_ps.w);
            const int   p  = p0;

            const float f0 = (float)(p / 9 - 1);
            const float f1 = (float)((p / 3) % 3 - 1);
            const float f2 = (float)(p % 3 - 1);

            const float* C = s_cells + g * 9;
            const float tx = C[0]*f0 + C[3]*f1 + C[6]*f2;
            const float ty = C[1]*f0 + C[4]*f1 + C[7]*f2;
            const float tz = C[2]*f0 + C[5]*f1 + C[8]*f2;

            const float vx = sx - dx + tx;
            const float vy = sy - dy + ty;
            const float vz = sz - dz + tz;

            const float len  = sqrtf(vx*vx + vy*vy + vz*vz);
            const float invl = __builtin_amdgcn_rcpf(fmaxf(len, 1e-6f));
            const float x = vx * invl, y = vy * invl, z = vz * invl;

            row[0] = len;
            row[1] = 1.0f;
            row[2] = s3 * x;
            row[3] = s3 * y;
            row[4] = s3 * z;
            row[5] = s15 * x * z;
            row[6] = s15 * x * y;
            row[7] = s5  * (y*y - 0.5f*(x*x + z*z));
            row[8] = s15 * y * z;
            row[9] = 0.5f * s15 * (z*z - x*x);

            // polynomial cutoff (P=6): 1 - 28 x^6 + 48 x^7 - 21 x^8
            const float xc = fminf(len * (1.0f/6.0f), 1.0f);
            const float x3 = xc * xc * xc;
            const float x6 = x3 * x3;
            const float cut = fmaf(x6, fmaf(xc, fmaf(-21.0f, xc, 48.0f), -28.0f), 1.0f);
            row[10] = cut;

            // bessel via Chebyshev recurrence; native sin/cos (~1e-5 err, tol 0.125)
            const float safe = fminf(fmaxf(len, 1e-6f), 6.0f);
            const float a = safe * 0.5235987755982988f;   // pi/6
            const float sa = __sinf(a);
            const float ca = __cosf(a);
            const float w = cut * 0.5f * __builtin_amdgcn_rcpf(safe);
            const float two_ca = 2.0f * ca;
            float s_prev = 0.0f, s_cur = sa;
            row[11] = s_cur * w;
            #pragma unroll
            for (int n = 2; n <= 8; ++n) {
                const float s_next = two_ca * s_cur - s_prev;
                s_prev = s_cur;
                s_cur  = s_next;
                row[10 + n] = s_cur * w;
            }
        }

        // 4) stage (after all threads finished the copyout above)
        __syncthreads();
        #pragma unroll
        for (int j = 0; j < 19; ++j) s_out[tid * 19 + j] = row[j];   // stride 19: conflict-free
        __syncthreads();

        // 5) rotate pipeline
        g_ps = n_ps; g_pd = n_pd;
        p0 = p1;
        src1 = src2; dst1 = dst2; p1 = p2;
        tprev = t;
    }

    // epilogue: flush the last staged tile
    if (tprev >= 0) {
        const int nvalid  = min(BLOCK, E - tprev * BLOCK);
        const int nfloats = nvalid * 19;
        float* gout = out + (size_t)tprev * BLOCK * 19;
        const int n4 = nfloats >> 2;
        const vf4* s4 = reinterpret_cast<const vf4*>(s_out);
        vf4* g4 = reinterpret_cast<vf4*>(gout);
        for (int i = tid; i < n4; i += BLOCK)
            __builtin_nontemporal_store(s4[i], g4 + i);
        for (int i = (n4 << 2) + tid; i < nfloats; i += BLOCK)
            __builtin_nontemporal_store(s_out[i], gout + i);
    }
}

extern "C" void kernel_launch(void* const* d_in, const int* in_sizes, int n_in,
                              void* d_out, int out_size, void* d_ws, size_t ws_size,
                              hipStream_t stream) {
    const float* pos   = (const float*)d_in[0];
    const float* cells = (const float*)d_in[1];
    const int*   eidx  = (const int*)d_in[2];
    const int*   pidx  = (const int*)d_in[3];
    const int*   batch = (const int*)d_in[4];
    float* out = (float*)d_out;

    const int E = in_sizes[3];   // periodic_index count = num edges
    const int N = in_sizes[4];   // batch count = num nodes
    const int ntiles = (E + BLOCK - 1) / BLOCK;
    const int grid = ntiles < NBLOCKS ? ntiles : NBLOCKS;

    if (d_ws != nullptr && ws_size >= (size_t)N * sizeof(vf4)) {
        vf4* pos4 = (vf4*)d_ws;
        const int pgrid = (N + BLOCK - 1) / BLOCK;
        pack_pos_batch<<<pgrid, BLOCK, 0, stream>>>(pos, batch, pos4, N);
        edge_encoding_kernel<true><<<grid, BLOCK, 0, stream>>>(
            pos, pos4, cells, eidx, pidx, batch, out, E);
    } else {
        edge_encoding_kernel<false><<<grid, BLOCK, 0, stream>>>(
            pos, nullptr, cells, eidx, pidx, batch, out, E);
    }
}